// Round 1
// baseline (613.193 us; speedup 1.0000x reference)
//
#include <hip/hip_runtime.h>
#include <hip/hip_bf16.h>

#define BB 4
#define LL 1024
#define DIMD 512
#define HH 8
#define EHD 64
#define NBUCK 1023

// ---------------------------------------------------------------------------
// GEMM: C[m][n] = sum_k A[m][k] * W[n][k] + bias[n]   (A: MxK, W: NxK, both row-major)
// 64x64 block tile, BK=16, 256 threads, 4x4 micro-tile per thread.
// WRITE_MODE 0: write C row-major MxN to out0.
// WRITE_MODE 1: qkv scatter — n<512 -> q, <1024 -> k, else v, laid out (B,H,L,EH).
// ---------------------------------------------------------------------------
template<int WRITE_MODE>
__global__ __launch_bounds__(256) void gemm_nt(const float* __restrict__ A,
                                               const float* __restrict__ W,
                                               const float* __restrict__ bias,
                                               float* __restrict__ out0,
                                               float* __restrict__ out1,
                                               float* __restrict__ out2,
                                               int M, int N, int K)
{
    __shared__ float As[16][68];   // [k][m], +4 pad keeps rows 16B-aligned
    __shared__ float Bs[16][68];   // [k][n]
    const int t = threadIdx.x;
    const int m0 = blockIdx.x * 64;
    const int n0 = blockIdx.y * 64;
    const int tx = t & 15, ty = t >> 4;
    const int lrow = t >> 2;          // 0..63
    const int lk4  = (t & 3) * 4;     // 0,4,8,12

    float acc[4][4] = {};

    for (int k0 = 0; k0 < K; k0 += 16) {
        float4 av = *(const float4*)&A[(size_t)(m0 + lrow) * K + k0 + lk4];
        float4 wv = *(const float4*)&W[(size_t)(n0 + lrow) * K + k0 + lk4];
        As[lk4+0][lrow] = av.x; As[lk4+1][lrow] = av.y;
        As[lk4+2][lrow] = av.z; As[lk4+3][lrow] = av.w;
        Bs[lk4+0][lrow] = wv.x; Bs[lk4+1][lrow] = wv.y;
        Bs[lk4+2][lrow] = wv.z; Bs[lk4+3][lrow] = wv.w;
        __syncthreads();
        #pragma unroll
        for (int kk = 0; kk < 16; ++kk) {
            float4 a4 = *(const float4*)&As[kk][ty * 4];
            float4 b4 = *(const float4*)&Bs[kk][tx * 4];
            acc[0][0] += a4.x * b4.x; acc[0][1] += a4.x * b4.y;
            acc[0][2] += a4.x * b4.z; acc[0][3] += a4.x * b4.w;
            acc[1][0] += a4.y * b4.x; acc[1][1] += a4.y * b4.y;
            acc[1][2] += a4.y * b4.z; acc[1][3] += a4.y * b4.w;
            acc[2][0] += a4.z * b4.x; acc[2][1] += a4.z * b4.y;
            acc[2][2] += a4.z * b4.z; acc[2][3] += a4.z * b4.w;
            acc[3][0] += a4.w * b4.x; acc[3][1] += a4.w * b4.y;
            acc[3][2] += a4.w * b4.z; acc[3][3] += a4.w * b4.w;
        }
        __syncthreads();
    }

    float bx = bias[n0 + tx * 4 + 0];
    float by = bias[n0 + tx * 4 + 1];
    float bz = bias[n0 + tx * 4 + 2];
    float bw = bias[n0 + tx * 4 + 3];

    if (WRITE_MODE == 0) {
        #pragma unroll
        for (int i = 0; i < 4; ++i) {
            int m = m0 + ty * 4 + i;
            float4 v;
            v.x = acc[i][0] + bx; v.y = acc[i][1] + by;
            v.z = acc[i][2] + bz; v.w = acc[i][3] + bw;
            *(float4*)&out0[(size_t)m * N + n0 + tx * 4] = v;
        }
    } else {
        // n0 is a multiple of 64 -> whole block maps to one {q,k,v} and one head
        const int which = n0 >> 9;
        const int h = (n0 >> 6) & 7;
        float* dst = (which == 0) ? out0 : (which == 1) ? out1 : out2;
        #pragma unroll
        for (int i = 0; i < 4; ++i) {
            int m = m0 + ty * 4 + i;
            int b = m >> 10, l = m & (LL - 1);
            float4 v;
            v.x = acc[i][0] + bx; v.y = acc[i][1] + by;
            v.z = acc[i][2] + bz; v.w = acc[i][3] + bw;
            *(float4*)&dst[(((size_t)(b * HH + h)) * LL + l) * EHD + tx * 4] = v;
        }
    }
}

// ---------------------------------------------------------------------------
// RoPE in place on q and k, (B,H,L,EH) layout, half = 32.
// one thread per (b,h,l,e<32) pair.
// ---------------------------------------------------------------------------
__global__ __launch_bounds__(256) void rope_k(float* __restrict__ qs,
                                              float* __restrict__ ks,
                                              const int* __restrict__ time_ids)
{
    int idx = blockIdx.x * 256 + threadIdx.x;   // B*H*L*32 = 1048576
    int e = idx & 31;
    int l = (idx >> 5) & (LL - 1);
    int h = (idx >> 15) & (HH - 1);
    int b = idx >> 18;
    int tt = time_ids[b * LL + l];
    float inv = powf(10000.f, -(float)e / 32.f);
    float ang = (float)tt * inv;
    float c, s;
    sincosf(ang, &s, &c);
    size_t base = (((size_t)(b * HH + h)) * LL + l) * EHD + e;
    float q1 = qs[base], q2 = qs[base + 32];
    qs[base]      = q1 * c - q2 * s;
    qs[base + 32] = q2 * c + q1 * s;
    float k1 = ks[base], k2 = ks[base + 32];
    ks[base]      = k1 * c - k2 * s;
    ks[base + 32] = k2 * c + k1 * s;
}

// ---------------------------------------------------------------------------
// Attention: one block per (b*H+h, 32-row q tile). Online softmax over k tiles
// of 32, plus the post_bias (non-softmax) accumulation in the same pass.
// mask is all-true in this problem -> ignored.
// ---------------------------------------------------------------------------
__global__ __launch_bounds__(256) void attn_k(const float* __restrict__ qs,
                                              const float* __restrict__ ks,
                                              const float* __restrict__ vs,
                                              const int* __restrict__ time_ids,
                                              const float* __restrict__ rel_table,
                                              const float* __restrict__ post_table,
                                              float* __restrict__ ao)
{
    __shared__ float Q[32][65];
    __shared__ float Kt[32][65];
    __shared__ float Vt[32][68];
    __shared__ float S[32][33];
    __shared__ float PB[32][33];
    __shared__ float mstate[32], dstate[32], fstate[32];
    __shared__ int tq[32], tk[32];

    const int t = threadIdx.x;
    const int bh = blockIdx.x;
    const int b = bh >> 3, h = bh & 7;
    const int q0 = blockIdx.y * 32;
    const float* qb = qs + (size_t)bh * LL * EHD;
    const float* kb = ks + (size_t)bh * LL * EHD;
    const float* vb = vs + (size_t)bh * LL * EHD;
    const float* rt = rel_table + h * NBUCK;
    const float* pt = post_table + h * NBUCK;

    #pragma unroll
    for (int chunk = 0; chunk < 8; ++chunk) {
        int flat = chunk * 256 + t;
        int r = flat >> 6, e = flat & 63;
        Q[r][e] = qb[(size_t)(q0 + r) * EHD + e];
    }
    if (t < 32) {
        tq[t] = time_ids[b * LL + q0 + t];
        mstate[t] = -1e30f;
        dstate[t] = 0.f;
    }

    float acc1[8] = {};
    float acc2[8] = {};
    const int e = t & 63, g = t >> 6;

    for (int kt = 0; kt < LL / 32; ++kt) {
        const int k0 = kt * 32;
        __syncthreads();
        #pragma unroll
        for (int chunk = 0; chunk < 8; ++chunk) {
            int flat = chunk * 256 + t;
            int r = flat >> 6, ee = flat & 63;
            Kt[r][ee] = kb[(size_t)(k0 + r) * EHD + ee];
            Vt[r][ee] = vb[(size_t)(k0 + r) * EHD + ee];
        }
        if (t < 32) tk[t] = time_ids[b * LL + k0 + t];
        __syncthreads();

        // scores + bias lookup
        {
            const int c = t & 31;
            const int rbase = (t >> 5) * 4;
            float d0 = 0, d1 = 0, d2 = 0, d3 = 0;
            #pragma unroll
            for (int x = 0; x < 64; ++x) {
                float kv = Kt[c][x];
                d0 += Q[rbase + 0][x] * kv;
                d1 += Q[rbase + 1][x] * kv;
                d2 += Q[rbase + 2][x] * kv;
                d3 += Q[rbase + 3][x] * kv;
            }
            const int tc = tk[c];
            float dd[4] = {d0, d1, d2, d3};
            #pragma unroll
            for (int i = 0; i < 4; ++i) {
                int r = rbase + i;
                int diff = tq[r] - tc + 511;
                diff = min(max(diff, 0), 1022);
                S[r][c] = dd[i] * 0.125f + rt[diff];
                PB[r][c] = pt[diff];
            }
        }
        __syncthreads();

        if (t < 32) {
            float mx = -1e30f;
            for (int c = 0; c < 32; ++c) mx = fmaxf(mx, S[t][c]);
            float mold = mstate[t];
            float mnew = fmaxf(mold, mx);
            fstate[t] = expf(mold - mnew);
            mstate[t] = mnew;
        }
        __syncthreads();

        #pragma unroll
        for (int chunk = 0; chunk < 4; ++chunk) {
            int flat = chunk * 256 + t;
            int r = flat >> 5, c = flat & 31;
            S[r][c] = expf(S[r][c] - mstate[r]);
        }
        __syncthreads();

        if (t < 32) {
            float ssum = 0;
            for (int c = 0; c < 32; ++c) ssum += S[t][c];
            dstate[t] = dstate[t] * fstate[t] + ssum;
        }

        #pragma unroll
        for (int i = 0; i < 8; ++i) acc1[i] *= fstate[g * 8 + i];
        for (int c = 0; c < 32; ++c) {
            float vv = Vt[c][e];
            #pragma unroll
            for (int i = 0; i < 8; ++i) {
                int r = g * 8 + i;
                acc1[i] += S[r][c] * vv;
                acc2[i] += PB[r][c] * vv;
            }
        }
    }
    __syncthreads();

    #pragma unroll
    for (int i = 0; i < 8; ++i) {
        int r = g * 8 + i;
        float o = acc1[i] / dstate[r] + acc2[i];
        ao[((size_t)(b * LL + q0 + r)) * DIMD + h * EHD + e] = o;
    }
}

extern "C" void kernel_launch(void* const* d_in, const int* in_sizes, int n_in,
                              void* d_out, int out_size, void* d_ws, size_t ws_size,
                              hipStream_t stream)
{
    const float* x        = (const float*)d_in[0];
    // d_in[1] = mask: all-true in this problem, unused
    const int*   time_ids = (const int*)d_in[2];
    const float* W_in     = (const float*)d_in[3];
    const float* b_in     = (const float*)d_in[4];
    const float* W_out    = (const float*)d_in[5];
    const float* b_out    = (const float*)d_in[6];
    const float* rel_t    = (const float*)d_in[7];
    const float* post_t   = (const float*)d_in[8];
    float* out = (float*)d_out;

    float* ws = (float*)d_ws;
    const size_t PANEL = (size_t)BB * HH * LL * EHD;   // 2,097,152 floats
    float* qs = ws;
    float* ks = ws + PANEL;
    float* vs = ws + 2 * PANEL;
    float* ao = ws + 3 * PANEL;

    // qkv = x @ W_in^T  (+ b_in), scattered into (B,H,L,EH) q/k/v panels
    gemm_nt<1><<<dim3(64, 24), 256, 0, stream>>>(x, W_in, b_in, qs, ks, vs,
                                                 BB * LL, 3 * DIMD, DIMD);
    // RoPE in place on q, k
    rope_k<<<4096, 256, 0, stream>>>(qs, ks, time_ids);
    // attention + post-bias accumulation -> ao in (B,L,H*EH) layout
    attn_k<<<dim3(32, 32), 256, 0, stream>>>(qs, ks, vs, time_ids, rel_t, post_t, ao);
    // out = ao @ W_out^T + b_out
    gemm_nt<0><<<dim3(64, 8), 256, 0, stream>>>(ao, W_out, b_out, out,
                                                nullptr, nullptr,
                                                BB * LL, DIMD, DIMD);
}

// Round 2
// 204.557 us; speedup vs baseline: 2.9977x; 2.9977x over previous
//
#include <hip/hip_runtime.h>
#include <hip/hip_bf16.h>

#define BB 4
#define LL 1024
#define DIMD 512
#define HH 8
#define EHD 64
#define NBUCK 1023

using f32x4 = __attribute__((ext_vector_type(4))) float;
using s16x8 = __attribute__((ext_vector_type(8))) short;

__device__ __forceinline__ ushort to_bf16(float x) {
    union { float f; unsigned u; } v; v.f = x;
    unsigned r = (v.u + 0x7FFFu + ((v.u >> 16) & 1u)) >> 16;
    return (ushort)r;
}

// ---------------------------------------------------------------------------
// GEMM: C[m][n] = sum_k A[m][k] * W[n][k] + bias[n]
// WRITE_MODE 0: C row-major MxN -> out0 (f32)
// WRITE_MODE 1: qkv scatter: q,k -> f32 panels (B,H,L,EH); v -> bf16 panel
//               TRANSPOSED (B,H,EH,L) for attention's V^T B-fragments.
// ---------------------------------------------------------------------------
template<int WRITE_MODE>
__global__ __launch_bounds__(256) void gemm_nt(const float* __restrict__ A,
                                               const float* __restrict__ W,
                                               const float* __restrict__ bias,
                                               float* __restrict__ out0,
                                               float* __restrict__ out1,
                                               ushort* __restrict__ vt,
                                               int M, int N, int K)
{
    __shared__ float As[16][68];
    __shared__ float Bs[16][68];
    const int t = threadIdx.x;
    const int m0 = blockIdx.x * 64;
    const int n0 = blockIdx.y * 64;
    const int tx = t & 15, ty = t >> 4;
    const int lrow = t >> 2;
    const int lk4  = (t & 3) * 4;

    float acc[4][4] = {};

    for (int k0 = 0; k0 < K; k0 += 16) {
        float4 av = *(const float4*)&A[(size_t)(m0 + lrow) * K + k0 + lk4];
        float4 wv = *(const float4*)&W[(size_t)(n0 + lrow) * K + k0 + lk4];
        As[lk4+0][lrow] = av.x; As[lk4+1][lrow] = av.y;
        As[lk4+2][lrow] = av.z; As[lk4+3][lrow] = av.w;
        Bs[lk4+0][lrow] = wv.x; Bs[lk4+1][lrow] = wv.y;
        Bs[lk4+2][lrow] = wv.z; Bs[lk4+3][lrow] = wv.w;
        __syncthreads();
        #pragma unroll
        for (int kk = 0; kk < 16; ++kk) {
            float4 a4 = *(const float4*)&As[kk][ty * 4];
            float4 b4 = *(const float4*)&Bs[kk][tx * 4];
            acc[0][0] += a4.x * b4.x; acc[0][1] += a4.x * b4.y;
            acc[0][2] += a4.x * b4.z; acc[0][3] += a4.x * b4.w;
            acc[1][0] += a4.y * b4.x; acc[1][1] += a4.y * b4.y;
            acc[1][2] += a4.y * b4.z; acc[1][3] += a4.y * b4.w;
            acc[2][0] += a4.z * b4.x; acc[2][1] += a4.z * b4.y;
            acc[2][2] += a4.z * b4.z; acc[2][3] += a4.z * b4.w;
            acc[3][0] += a4.w * b4.x; acc[3][1] += a4.w * b4.y;
            acc[3][2] += a4.w * b4.z; acc[3][3] += a4.w * b4.w;
        }
        __syncthreads();
    }

    float bv[4];
    #pragma unroll
    for (int j = 0; j < 4; ++j) bv[j] = bias[n0 + tx * 4 + j];

    if (WRITE_MODE == 0) {
        #pragma unroll
        for (int i = 0; i < 4; ++i) {
            int m = m0 + ty * 4 + i;
            float4 v;
            v.x = acc[i][0] + bv[0]; v.y = acc[i][1] + bv[1];
            v.z = acc[i][2] + bv[2]; v.w = acc[i][3] + bv[3];
            *(float4*)&out0[(size_t)m * N + n0 + tx * 4] = v;
        }
    } else {
        const int which = n0 >> 9;
        const int h = (n0 >> 6) & 7;
        if (which < 2) {
            float* dst = (which == 0) ? out0 : out1;
            #pragma unroll
            for (int i = 0; i < 4; ++i) {
                int m = m0 + ty * 4 + i;
                int b = m >> 10, l = m & (LL - 1);
                float4 v;
                v.x = acc[i][0] + bv[0]; v.y = acc[i][1] + bv[1];
                v.z = acc[i][2] + bv[2]; v.w = acc[i][3] + bv[3];
                *(float4*)&dst[(((size_t)(b * HH + h)) * LL + l) * EHD + tx * 4] = v;
            }
        } else {
            // v -> bf16, transposed (B,H,EH,L)
            int m = m0 + ty * 4;
            int b = m >> 10, l = m & (LL - 1);
            #pragma unroll
            for (int j = 0; j < 4; ++j) {
                int e = tx * 4 + j;
                ushort4 pk;
                pk.x = to_bf16(acc[0][j] + bv[j]);
                pk.y = to_bf16(acc[1][j] + bv[j]);
                pk.z = to_bf16(acc[2][j] + bv[j]);
                pk.w = to_bf16(acc[3][j] + bv[j]);
                *(ushort4*)&vt[(((size_t)(b * HH + h)) * EHD + e) * LL + l] = pk;
            }
        }
    }
}

// ---------------------------------------------------------------------------
// RoPE: read f32 q/k panels, rotate, write bf16 panels (B,H,L,EH).
// ---------------------------------------------------------------------------
__global__ __launch_bounds__(256) void rope_bf16(const float* __restrict__ qs,
                                                 const float* __restrict__ ks,
                                                 ushort* __restrict__ qb,
                                                 ushort* __restrict__ kb,
                                                 const int* __restrict__ time_ids)
{
    int idx = blockIdx.x * 256 + threadIdx.x;   // B*H*L*32
    int e = idx & 31;
    int l = (idx >> 5) & (LL - 1);
    int h = (idx >> 15) & (HH - 1);
    int b = idx >> 18;
    int tt = time_ids[b * LL + l];
    float inv = powf(10000.f, -(float)e / 32.f);
    float ang = (float)tt * inv;
    float c, s;
    sincosf(ang, &s, &c);
    size_t base = (((size_t)(b * HH + h)) * LL + l) * EHD + e;
    float q1 = qs[base], q2 = qs[base + 32];
    qb[base]      = to_bf16(q1 * c - q2 * s);
    qb[base + 32] = to_bf16(q2 * c + q1 * s);
    float k1 = ks[base], k2 = ks[base + 32];
    kb[base]      = to_bf16(k1 * c - k2 * s);
    kb[base + 32] = to_bf16(k2 * c + k1 * s);
}

// ---------------------------------------------------------------------------
// MFMA attention. Block = (bh, 128-q-row tile), 8 waves x 16 q-rows.
// K-tiles of 64. K/V/P staged in XOR-swizzled LDS ((row&7)<<4 on byte addr).
// Both softmax path (online) and post-bias path accumulated via MFMA.
// ---------------------------------------------------------------------------
__global__ __launch_bounds__(512) void attn_mfma(const ushort* __restrict__ qb,
                                                 const ushort* __restrict__ kb,
                                                 const ushort* __restrict__ vt,
                                                 const int* __restrict__ time_ids,
                                                 const float* __restrict__ rel_table,
                                                 const float* __restrict__ post_table,
                                                 float* __restrict__ ao)
{
    __shared__ __align__(16) float rt_s[1024];
    __shared__ __align__(16) float pt_s[1024];
    __shared__ __align__(16) ushort Ks[4096];      // [64 k-rows][64 e] swizzled
    __shared__ __align__(16) ushort Vs[4096];      // [64 e-rows][64 k] swizzled (V^T)
    __shared__ __align__(16) ushort Ps[8][1024];   // per-wave [16 q][64 k] swizzled
    __shared__ int tq_s[128];
    __shared__ int tk_s[64];

    const int t = threadIdx.x;
    const int lane = t & 63;
    const int w = t >> 6;
    const int l15 = lane & 15, lg = lane >> 4;
    const int bh = blockIdx.x, b = bh >> 3, h = bh & 7;
    const int q0 = blockIdx.y * 128;

    for (int i = t; i < NBUCK; i += 512) {
        rt_s[i] = rel_table[h * NBUCK + i];
        pt_s[i] = post_table[h * NBUCK + i];
    }
    if (t < 128) tq_s[t] = time_ids[b * LL + q0 + t];

    const ushort* qpan = qb + (size_t)bh * LL * EHD;
    const ushort* kpan = kb + (size_t)bh * LL * EHD;
    const ushort* vpan = vt + (size_t)bh * EHD * LL;

    const int wq0 = q0 + w * 16;
    s16x8 qf[2];
    #pragma unroll
    for (int ec = 0; ec < 2; ++ec)
        qf[ec] = *(const s16x8*)&qpan[(size_t)(wq0 + l15) * EHD + ec * 32 + lg * 8];

    __syncthreads();
    int tqr[4];
    #pragma unroll
    for (int r = 0; r < 4; ++r) tqr[r] = tq_s[w * 16 + lg * 4 + r];

    float mrow[4], drow[4];
    f32x4 acc1[4], acc2[4];
    #pragma unroll
    for (int r = 0; r < 4; ++r) { mrow[r] = -1e30f; drow[r] = 0.f; }
    #pragma unroll
    for (int ei = 0; ei < 4; ++ei) {
        acc1[ei] = {0.f, 0.f, 0.f, 0.f};
        acc2[ei] = {0.f, 0.f, 0.f, 0.f};
    }

    ushort* ps = Ps[w];

    for (int kt = 0; kt < 16; ++kt) {
        const int k0 = kt * 64;
        __syncthreads();
        {   // stage K tile and V^T tile (each thread: one 16B chunk of each)
            int row = t >> 3, c16 = t & 7;
            uint4 kv = *(const uint4*)&kpan[(size_t)(k0 + row) * EHD + c16 * 8];
            *(uint4*)((char*)Ks + row * 128 + ((c16 * 16) ^ ((row & 7) << 4))) = kv;
            uint4 vv = *(const uint4*)&vpan[(size_t)row * LL + k0 + c16 * 8];
            *(uint4*)((char*)Vs + row * 128 + ((c16 * 16) ^ ((row & 7) << 4))) = vv;
        }
        if (t < 64) tk_s[t] = time_ids[b * LL + k0 + t];
        __syncthreads();

        // S = Q K^T  (16x64 per wave)
        f32x4 sc[4];
        #pragma unroll
        for (int ci = 0; ci < 4; ++ci) sc[ci] = {0.f, 0.f, 0.f, 0.f};
        #pragma unroll
        for (int ec = 0; ec < 2; ++ec) {
            #pragma unroll
            for (int ci = 0; ci < 4; ++ci) {
                int row = ci * 16 + l15;
                s16x8 kf = *(const s16x8*)((const char*)Ks + row * 128 +
                                           ((ec * 64 + lg * 16) ^ ((row & 7) << 4)));
                sc[ci] = __builtin_amdgcn_mfma_f32_16x16x32_bf16(qf[ec], kf, sc[ci], 0, 0, 0);
            }
        }

        int tkv[4];
        #pragma unroll
        for (int ci = 0; ci < 4; ++ci) tkv[ci] = tk_s[ci * 16 + l15];

        // bias add (scale*S + rel) and stage post-bias (bf16) into wave LDS
        #pragma unroll
        for (int ci = 0; ci < 4; ++ci) {
            #pragma unroll
            for (int r = 0; r < 4; ++r) {
                int idx = tqr[r] - tkv[ci] + 511;      // always in [0,1022]
                sc[ci][r] = sc[ci][r] * 0.125f + rt_s[idx];
                int row = lg * 4 + r;
                *(ushort*)((char*)ps + row * 128 + ((ci * 32 + l15 * 2) ^ ((row & 7) << 4)))
                    = to_bf16(pt_s[idx]);
            }
        }
        asm volatile("s_waitcnt lgkmcnt(0)" ::: "memory");

        // V^T B-fragments (shared by both PV passes)
        s16x8 vf[4][2];
        #pragma unroll
        for (int ei = 0; ei < 4; ++ei) {
            #pragma unroll
            for (int kc = 0; kc < 2; ++kc) {
                int row = ei * 16 + l15;
                vf[ei][kc] = *(const s16x8*)((const char*)Vs + row * 128 +
                                             ((kc * 64 + lg * 16) ^ ((row & 7) << 4)));
            }
        }
        // acc2 += PB @ V
        #pragma unroll
        for (int kc = 0; kc < 2; ++kc) {
            int row = l15;
            s16x8 af = *(const s16x8*)((const char*)ps + row * 128 +
                                       ((kc * 64 + lg * 16) ^ ((row & 7) << 4)));
            #pragma unroll
            for (int ei = 0; ei < 4; ++ei)
                acc2[ei] = __builtin_amdgcn_mfma_f32_16x16x32_bf16(af, vf[ei][kc], acc2[ei], 0, 0, 0);
        }

        // online softmax (wave-parallel, 16-lane shfl trees), P -> LDS bf16
        #pragma unroll
        for (int r = 0; r < 4; ++r) {
            float mx = fmaxf(fmaxf(sc[0][r], sc[1][r]), fmaxf(sc[2][r], sc[3][r]));
            #pragma unroll
            for (int d = 1; d < 16; d <<= 1) mx = fmaxf(mx, __shfl_xor(mx, d));
            float mnew = fmaxf(mrow[r], mx);
            float fs = __expf(mrow[r] - mnew);
            mrow[r] = mnew;
            float rsum = 0.f;
            #pragma unroll
            for (int ci = 0; ci < 4; ++ci) {
                float p = __expf(sc[ci][r] - mnew);
                sc[ci][r] = p;
                rsum += p;
            }
            #pragma unroll
            for (int d = 1; d < 16; d <<= 1) rsum += __shfl_xor(rsum, d);
            drow[r] = drow[r] * fs + rsum;
            #pragma unroll
            for (int ei = 0; ei < 4; ++ei) acc1[ei][r] *= fs;
            int row = lg * 4 + r;
            #pragma unroll
            for (int ci = 0; ci < 4; ++ci)
                *(ushort*)((char*)ps + row * 128 + ((ci * 32 + l15 * 2) ^ ((row & 7) << 4)))
                    = to_bf16(sc[ci][r]);
        }
        asm volatile("s_waitcnt lgkmcnt(0)" ::: "memory");

        // acc1 += P @ V
        #pragma unroll
        for (int kc = 0; kc < 2; ++kc) {
            int row = l15;
            s16x8 af = *(const s16x8*)((const char*)ps + row * 128 +
                                       ((kc * 64 + lg * 16) ^ ((row & 7) << 4)));
            #pragma unroll
            for (int ei = 0; ei < 4; ++ei)
                acc1[ei] = __builtin_amdgcn_mfma_f32_16x16x32_bf16(af, vf[ei][kc], acc1[ei], 0, 0, 0);
        }
    }

    // epilogue: O = acc1/d + acc2 -> ao (B,L,DIM) f32
    #pragma unroll
    for (int ei = 0; ei < 4; ++ei) {
        #pragma unroll
        for (int r = 0; r < 4; ++r) {
            int row = wq0 + lg * 4 + r;
            int col = h * EHD + ei * 16 + l15;
            ao[(size_t)(b * LL + row) * DIMD + col] = acc1[ei][r] / drow[r] + acc2[ei][r];
        }
    }
}

extern "C" void kernel_launch(void* const* d_in, const int* in_sizes, int n_in,
                              void* d_out, int out_size, void* d_ws, size_t ws_size,
                              hipStream_t stream)
{
    const float* x        = (const float*)d_in[0];
    const int*   time_ids = (const int*)d_in[2];
    const float* W_in     = (const float*)d_in[3];
    const float* b_in     = (const float*)d_in[4];
    const float* W_out    = (const float*)d_in[5];
    const float* b_out    = (const float*)d_in[6];
    const float* rel_t    = (const float*)d_in[7];
    const float* post_t   = (const float*)d_in[8];
    float* out = (float*)d_out;

    float* ws = (float*)d_ws;
    const size_t PANEL = (size_t)BB * HH * LL * EHD;     // 2,097,152
    float*  qs  = ws;
    float*  ks  = ws + PANEL;
    ushort* qbf = (ushort*)(ws + 2 * PANEL);
    ushort* kbf = (ushort*)(ws + 2 * PANEL + PANEL / 2);
    ushort* vtb = (ushort*)(ws + 2 * PANEL + PANEL);
    float*  ao  = ws;   // reuse qs after rope

    gemm_nt<1><<<dim3(64, 24), 256, 0, stream>>>(x, W_in, b_in, qs, ks, vtb,
                                                 BB * LL, 3 * DIMD, DIMD);
    rope_bf16<<<4096, 256, 0, stream>>>(qs, ks, qbf, kbf, time_ids);
    attn_mfma<<<dim3(32, 8), 512, 0, stream>>>(qbf, kbf, vtb, time_ids,
                                               rel_t, post_t, ao);
    gemm_nt<0><<<dim3(64, 8), 256, 0, stream>>>(ao, W_out, b_out, out,
                                                nullptr, nullptr,
                                                BB * LL, DIMD, DIMD);
}

// Round 3
// 87.397 us; speedup vs baseline: 7.0162x; 2.3406x over previous
//
#include <hip/hip_runtime.h>
#include <hip/hip_bf16.h>

#define BB 4
#define LL 1024
#define DIMD 512
#define HH 8
#define EHD 64
#define NBUCK 1023

using f32x4 = __attribute__((ext_vector_type(4))) float;
using s16x8 = __attribute__((ext_vector_type(8))) short;

__device__ __forceinline__ ushort to_bf16(float x) {
    union { float f; unsigned u; } v; v.f = x;
    unsigned r = (v.u + 0x7FFFu + ((v.u >> 16) & 1u)) >> 16;
    return (ushort)r;
}

__device__ __forceinline__ void gl_lds16(const ushort* g, ushort* l) {
    __builtin_amdgcn_global_load_lds(
        (const __attribute__((address_space(1))) unsigned int*)g,
        (__attribute__((address_space(3))) unsigned int*)l, 16, 0, 0);
}

// ---------------------------------------------------------------------------
// bf16 conversion of x, W_in, W_out (concatenated ranges)
// ---------------------------------------------------------------------------
#define XN  2097152
#define WIN 786432
#define WON 262144
__global__ __launch_bounds__(256) void cvt_bf16(const float* __restrict__ x,
                                                const float* __restrict__ wi,
                                                const float* __restrict__ wo,
                                                ushort* __restrict__ xb,
                                                ushort* __restrict__ wib,
                                                ushort* __restrict__ wob)
{
    int idx = (blockIdx.x * 256 + threadIdx.x) * 4;
    const float* src; ushort* dst; int off;
    if (idx < XN)            { src = x;  dst = xb;  off = idx; }
    else if (idx < XN + WIN) { src = wi; dst = wib; off = idx - XN; }
    else                     { src = wo; dst = wob; off = idx - XN - WIN; }
    float4 v = *(const float4*)&src[off];
    ushort4 o;
    o.x = to_bf16(v.x); o.y = to_bf16(v.y);
    o.z = to_bf16(v.z); o.w = to_bf16(v.w);
    *(ushort4*)&dst[off] = o;
}

// ---------------------------------------------------------------------------
// MFMA GEMM: C[m][n] = sum_k A[m][k]*B[n][k] + bias[n]; A,B bf16 row-major.
// BM=128, BK=64, 256 threads = 4 waves in 2x2 grid, each wave 64 x BN/2.
// WMODE 0: f32 C -> outf [M][N]
// WMODE 1: qkv epilogue. q,k: fused rope -> bf16 panels (B,H,L,EH).
//          v: LDS-transpose -> bf16 panel (B,H,EH,L).
// ---------------------------------------------------------------------------
template<int BN, int WMODE>
__global__ __launch_bounds__(256) void mfma_gemm(const ushort* __restrict__ A,
                                                 const ushort* __restrict__ B,
                                                 const float* __restrict__ bias,
                                                 float* __restrict__ outf,
                                                 ushort* __restrict__ outq,
                                                 ushort* __restrict__ outk,
                                                 ushort* __restrict__ outv,
                                                 const int* __restrict__ time_ids,
                                                 int M, int N, int K)
{
    constexpr int NREP = BN / 32;
    constexpr int SMEM_SZ = (WMODE == 1) ? 34816 : (16384 + BN * 128);
    __shared__ __align__(16) char smem[SMEM_SZ];
    ushort* Abuf = (ushort*)smem;              // [128][64]
    ushort* Bbuf = (ushort*)(smem + 16384);    // [BN][64]

    const int t = threadIdx.x;
    const int lane = t & 63;
    const int w = t >> 6;
    const int l15 = lane & 15, lg = lane >> 4;
    const int wr = w >> 1, wc = w & 1;
    const int m0 = blockIdx.x * 128;
    const int n0 = blockIdx.y * BN;

    const int asub = lane >> 3;
    const int kc8 = (lane & 7) * 8;
    const int arow_base = w * 32;
    const int brow_base = w * (BN / 4);

    f32x4 acc[4][NREP];
    #pragma unroll
    for (int mf = 0; mf < 4; ++mf)
        #pragma unroll
        for (int nf = 0; nf < NREP; ++nf)
            acc[mf][nf] = {0.f, 0.f, 0.f, 0.f};

    for (int k0 = 0; k0 < K; k0 += 64) {
        #pragma unroll
        for (int i = 0; i < 4; ++i) {
            int row = arow_base + i * 8;
            gl_lds16(&A[(size_t)(m0 + row + asub) * K + k0 + kc8], &Abuf[row * 64]);
        }
        #pragma unroll
        for (int i = 0; i < BN / 32; ++i) {
            int row = brow_base + i * 8;
            gl_lds16(&B[(size_t)(n0 + row + asub) * K + k0 + kc8], &Bbuf[row * 64]);
        }
        __syncthreads();
        #pragma unroll
        for (int kk = 0; kk < 2; ++kk) {
            s16x8 af[4], bf[NREP];
            #pragma unroll
            for (int mf = 0; mf < 4; ++mf)
                af[mf] = *(const s16x8*)&Abuf[(wr * 64 + mf * 16 + l15) * 64 + kk * 32 + lg * 8];
            #pragma unroll
            for (int nf = 0; nf < NREP; ++nf)
                bf[nf] = *(const s16x8*)&Bbuf[(wc * (BN / 2) + nf * 16 + l15) * 64 + kk * 32 + lg * 8];
            #pragma unroll
            for (int mf = 0; mf < 4; ++mf)
                #pragma unroll
                for (int nf = 0; nf < NREP; ++nf)
                    acc[mf][nf] = __builtin_amdgcn_mfma_f32_16x16x32_bf16(af[mf], bf[nf], acc[mf][nf], 0, 0, 0);
        }
        __syncthreads();
    }

    if (WMODE == 0) {
        float bv[NREP];
        #pragma unroll
        for (int nf = 0; nf < NREP; ++nf) bv[nf] = bias[n0 + wc * (BN / 2) + nf * 16 + l15];
        #pragma unroll
        for (int mf = 0; mf < 4; ++mf)
            #pragma unroll
            for (int r = 0; r < 4; ++r) {
                int m = m0 + wr * 64 + mf * 16 + lg * 4 + r;
                #pragma unroll
                for (int nf = 0; nf < NREP; ++nf)
                    outf[(size_t)m * N + n0 + wc * (BN / 2) + nf * 16 + l15] = acc[mf][nf][r] + bv[nf];
            }
    } else {
        const int which = n0 >> 9;
        if (which < 2) {
            // q or k: fused rope, write bf16 panel (B,H,L,EH)
            const int h = ((n0 & 511) + wc * 64) >> 6;
            ushort* dst = (which == 0) ? outq : outk;
            float bv[4];
            #pragma unroll
            for (int nf = 0; nf < 4; ++nf) bv[nf] = bias[n0 + wc * 64 + nf * 16 + l15];
            const float L2E = 13.287712379549449f;  // log2(10000)
            float inv0 = exp2f(-(float)(l15)      * (L2E / 32.f));
            float inv1 = exp2f(-(float)(16 + l15) * (L2E / 32.f));
            #pragma unroll
            for (int mf = 0; mf < 4; ++mf)
                #pragma unroll
                for (int r = 0; r < 4; ++r) {
                    int m = m0 + wr * 64 + mf * 16 + lg * 4 + r;
                    int b = m >> 10, li = m & (LL - 1);
                    int tt = time_ids[b * LL + li];
                    size_t rowbase = (((size_t)(b * HH + h)) * LL + li) * EHD;
                    #pragma unroll
                    for (int nf = 0; nf < 2; ++nf) {
                        float ang = (float)tt * (nf ? inv1 : inv0);
                        float c, s;
                        sincosf(ang, &s, &c);
                        float v1 = acc[mf][nf][r] + bv[nf];
                        float v2 = acc[mf][nf + 2][r] + bv[nf + 2];
                        dst[rowbase + nf * 16 + l15]      = to_bf16(v1 * c - v2 * s);
                        dst[rowbase + 32 + nf * 16 + l15] = to_bf16(v2 * c + v1 * s);
                    }
                }
        } else {
            // v: transpose via LDS (pitch 136), coalesced store (B,H,EH,L)
            ushort* T = (ushort*)smem;   // [128][136]
            float bv[4];
            #pragma unroll
            for (int nf = 0; nf < 4; ++nf) bv[nf] = bias[n0 + wc * 64 + nf * 16 + l15];
            #pragma unroll
            for (int mf = 0; mf < 4; ++mf)
                #pragma unroll
                for (int nf = 0; nf < 4; ++nf) {
                    int n = wc * 64 + nf * 16 + l15;
                    int mb = wr * 64 + mf * 16 + lg * 4;
                    ushort4 pk;
                    pk.x = to_bf16(acc[mf][nf][0] + bv[nf]);
                    pk.y = to_bf16(acc[mf][nf][1] + bv[nf]);
                    pk.z = to_bf16(acc[mf][nf][2] + bv[nf]);
                    pk.w = to_bf16(acc[mf][nf][3] + bv[nf]);
                    *(ushort4*)&T[n * 136 + mb] = pk;
                }
            __syncthreads();
            const int b = m0 >> 10, li0 = m0 & (LL - 1);
            const int hbase = (n0 & 511) >> 6;
            #pragma unroll
            for (int it = 0; it < 8; ++it) {
                int n = it * 16 + (t >> 4);
                int mc = (t & 15) * 8;
                uint4 val = *(const uint4*)&T[n * 136 + mc];
                int h = hbase + (n >> 6);
                int e = n & 63;
                *(uint4*)&outv[(((size_t)(b * HH + h)) * EHD + e) * LL + li0 + mc] = val;
            }
        }
    }
}

// ---------------------------------------------------------------------------
// MFMA attention (unchanged structure; epilogue now writes bf16).
// ---------------------------------------------------------------------------
__global__ __launch_bounds__(512) void attn_mfma(const ushort* __restrict__ qb,
                                                 const ushort* __restrict__ kb,
                                                 const ushort* __restrict__ vt,
                                                 const int* __restrict__ time_ids,
                                                 const float* __restrict__ rel_table,
                                                 const float* __restrict__ post_table,
                                                 ushort* __restrict__ ao)
{
    __shared__ __align__(16) float rt_s[1024];
    __shared__ __align__(16) float pt_s[1024];
    __shared__ __align__(16) ushort Ks[4096];
    __shared__ __align__(16) ushort Vs[4096];
    __shared__ __align__(16) ushort Ps[8][1024];
    __shared__ int tq_s[128];
    __shared__ int tk_s[64];

    const int t = threadIdx.x;
    const int lane = t & 63;
    const int w = t >> 6;
    const int l15 = lane & 15, lg = lane >> 4;
    const int bh = blockIdx.x, b = bh >> 3, h = bh & 7;
    const int q0 = blockIdx.y * 128;

    for (int i = t; i < NBUCK; i += 512) {
        rt_s[i] = rel_table[h * NBUCK + i];
        pt_s[i] = post_table[h * NBUCK + i];
    }
    if (t < 128) tq_s[t] = time_ids[b * LL + q0 + t];

    const ushort* qpan = qb + (size_t)bh * LL * EHD;
    const ushort* kpan = kb + (size_t)bh * LL * EHD;
    const ushort* vpan = vt + (size_t)bh * EHD * LL;

    const int wq0 = q0 + w * 16;
    s16x8 qf[2];
    #pragma unroll
    for (int ec = 0; ec < 2; ++ec)
        qf[ec] = *(const s16x8*)&qpan[(size_t)(wq0 + l15) * EHD + ec * 32 + lg * 8];

    __syncthreads();
    int tqr[4];
    #pragma unroll
    for (int r = 0; r < 4; ++r) tqr[r] = tq_s[w * 16 + lg * 4 + r];

    float mrow[4], drow[4];
    f32x4 acc1[4], acc2[4];
    #pragma unroll
    for (int r = 0; r < 4; ++r) { mrow[r] = -1e30f; drow[r] = 0.f; }
    #pragma unroll
    for (int ei = 0; ei < 4; ++ei) {
        acc1[ei] = {0.f, 0.f, 0.f, 0.f};
        acc2[ei] = {0.f, 0.f, 0.f, 0.f};
    }

    ushort* ps = Ps[w];

    for (int kt = 0; kt < 16; ++kt) {
        const int k0 = kt * 64;
        __syncthreads();
        {
            int row = t >> 3, c16 = t & 7;
            uint4 kv = *(const uint4*)&kpan[(size_t)(k0 + row) * EHD + c16 * 8];
            *(uint4*)((char*)Ks + row * 128 + ((c16 * 16) ^ ((row & 7) << 4))) = kv;
            uint4 vv = *(const uint4*)&vpan[(size_t)row * LL + k0 + c16 * 8];
            *(uint4*)((char*)Vs + row * 128 + ((c16 * 16) ^ ((row & 7) << 4))) = vv;
        }
        if (t < 64) tk_s[t] = time_ids[b * LL + k0 + t];
        __syncthreads();

        f32x4 sc[4];
        #pragma unroll
        for (int ci = 0; ci < 4; ++ci) sc[ci] = {0.f, 0.f, 0.f, 0.f};
        #pragma unroll
        for (int ec = 0; ec < 2; ++ec) {
            #pragma unroll
            for (int ci = 0; ci < 4; ++ci) {
                int row = ci * 16 + l15;
                s16x8 kf = *(const s16x8*)((const char*)Ks + row * 128 +
                                           ((ec * 64 + lg * 16) ^ ((row & 7) << 4)));
                sc[ci] = __builtin_amdgcn_mfma_f32_16x16x32_bf16(qf[ec], kf, sc[ci], 0, 0, 0);
            }
        }

        int tkv[4];
        #pragma unroll
        for (int ci = 0; ci < 4; ++ci) tkv[ci] = tk_s[ci * 16 + l15];

        #pragma unroll
        for (int ci = 0; ci < 4; ++ci) {
            #pragma unroll
            for (int r = 0; r < 4; ++r) {
                int idx = tqr[r] - tkv[ci] + 511;
                sc[ci][r] = sc[ci][r] * 0.125f + rt_s[idx];
                int row = lg * 4 + r;
                *(ushort*)((char*)ps + row * 128 + ((ci * 32 + l15 * 2) ^ ((row & 7) << 4)))
                    = to_bf16(pt_s[idx]);
            }
        }
        asm volatile("s_waitcnt lgkmcnt(0)" ::: "memory");

        s16x8 vf[4][2];
        #pragma unroll
        for (int ei = 0; ei < 4; ++ei) {
            #pragma unroll
            for (int kc = 0; kc < 2; ++kc) {
                int row = ei * 16 + l15;
                vf[ei][kc] = *(const s16x8*)((const char*)Vs + row * 128 +
                                             ((kc * 64 + lg * 16) ^ ((row & 7) << 4)));
            }
        }
        #pragma unroll
        for (int kc = 0; kc < 2; ++kc) {
            int row = l15;
            s16x8 af = *(const s16x8*)((const char*)ps + row * 128 +
                                       ((kc * 64 + lg * 16) ^ ((row & 7) << 4)));
            #pragma unroll
            for (int ei = 0; ei < 4; ++ei)
                acc2[ei] = __builtin_amdgcn_mfma_f32_16x16x32_bf16(af, vf[ei][kc], acc2[ei], 0, 0, 0);
        }

        #pragma unroll
        for (int r = 0; r < 4; ++r) {
            float mx = fmaxf(fmaxf(sc[0][r], sc[1][r]), fmaxf(sc[2][r], sc[3][r]));
            #pragma unroll
            for (int d = 1; d < 16; d <<= 1) mx = fmaxf(mx, __shfl_xor(mx, d));
            float mnew = fmaxf(mrow[r], mx);
            float fs = __expf(mrow[r] - mnew);
            mrow[r] = mnew;
            float rsum = 0.f;
            #pragma unroll
            for (int ci = 0; ci < 4; ++ci) {
                float p = __expf(sc[ci][r] - mnew);
                sc[ci][r] = p;
                rsum += p;
            }
            #pragma unroll
            for (int d = 1; d < 16; d <<= 1) rsum += __shfl_xor(rsum, d);
            drow[r] = drow[r] * fs + rsum;
            #pragma unroll
            for (int ei = 0; ei < 4; ++ei) acc1[ei][r] *= fs;
            int row = lg * 4 + r;
            #pragma unroll
            for (int ci = 0; ci < 4; ++ci)
                *(ushort*)((char*)ps + row * 128 + ((ci * 32 + l15 * 2) ^ ((row & 7) << 4)))
                    = to_bf16(sc[ci][r]);
        }
        asm volatile("s_waitcnt lgkmcnt(0)" ::: "memory");

        #pragma unroll
        for (int kc = 0; kc < 2; ++kc) {
            int row = l15;
            s16x8 af = *(const s16x8*)((const char*)ps + row * 128 +
                                       ((kc * 64 + lg * 16) ^ ((row & 7) << 4)));
            #pragma unroll
            for (int ei = 0; ei < 4; ++ei)
                acc1[ei] = __builtin_amdgcn_mfma_f32_16x16x32_bf16(af, vf[ei][kc], acc1[ei], 0, 0, 0);
        }
    }

    #pragma unroll
    for (int ei = 0; ei < 4; ++ei) {
        #pragma unroll
        for (int r = 0; r < 4; ++r) {
            int row = wq0 + lg * 4 + r;
            int col = h * EHD + ei * 16 + l15;
            ao[(size_t)(b * LL + row) * DIMD + col] = to_bf16(acc1[ei][r] / drow[r] + acc2[ei][r]);
        }
    }
}

extern "C" void kernel_launch(void* const* d_in, const int* in_sizes, int n_in,
                              void* d_out, int out_size, void* d_ws, size_t ws_size,
                              hipStream_t stream)
{
    const float* x        = (const float*)d_in[0];
    const int*   time_ids = (const int*)d_in[2];
    const float* W_in     = (const float*)d_in[3];
    const float* b_in     = (const float*)d_in[4];
    const float* W_out    = (const float*)d_in[5];
    const float* b_out    = (const float*)d_in[6];
    const float* rel_t    = (const float*)d_in[7];
    const float* post_t   = (const float*)d_in[8];
    float* out = (float*)d_out;

    ushort* wsu = (ushort*)d_ws;
    ushort* xb  = wsu;                 // 2,097,152
    ushort* wib = xb + XN;             // 786,432
    ushort* wob = wib + WIN;           // 262,144
    ushort* qbf = wob + WON;           // 2,097,152
    ushort* kbf = qbf + XN;
    ushort* vtb = kbf + XN;
    ushort* aob = vtb + XN;

    cvt_bf16<<<3072, 256, 0, stream>>>(x, W_in, W_out, xb, wib, wob);
    mfma_gemm<128, 1><<<dim3(32, 12), 256, 0, stream>>>(xb, wib, b_in,
                                                        nullptr, qbf, kbf, vtb,
                                                        time_ids,
                                                        BB * LL, 3 * DIMD, DIMD);
    attn_mfma<<<dim3(32, 8), 512, 0, stream>>>(qbf, kbf, vtb, time_ids,
                                               rel_t, post_t, aob);
    mfma_gemm<64, 0><<<dim3(32, 8), 256, 0, stream>>>(aob, wob, b_out,
                                                      out, nullptr, nullptr, nullptr,
                                                      nullptr,
                                                      BB * LL, DIMD, DIMD);
}